// Round 18
// baseline (1370.381 us; speedup 1.0000x reference)
//
#include <hip/hip_runtime.h>
#include <cstdint>

constexpr int NB   = 8;
constexpr int S    = 1024;
constexpr int CD   = 128;
constexpr int DIN  = 512;
constexpr int BATCH= 16;
constexpr int T    = 4096;
constexpr int NTOK = BATCH * T;        // 65536
constexpr int FCAP = 24;
constexpr float MARGIN = 4e-3f;        // > 2 * 1.3e-3 worst-case bf16 approx error

typedef __attribute__((ext_vector_type(8))) short bf16x8;
typedef __attribute__((ext_vector_type(4))) float f32x4;

__device__ __forceinline__ unsigned short f2bf(float f) {
  unsigned int u = __float_as_uint(f);
  return (unsigned short)((u + 0x7fffu + ((u >> 16) & 1u)) >> 16);
}
// order-preserving float<->uint for atomicMin (finite values)
__device__ __forceinline__ unsigned int fenc(float f) {
  unsigned int u = __float_as_uint(f);
  return (u & 0x80000000u) ? ~u : (u | 0x80000000u);
}
__device__ __forceinline__ float fdec(unsigned int e) {
  return (e & 0x80000000u) ? __uint_as_float(e ^ 0x80000000u) : __uint_as_float(~e);
}

// ---------------------------------------------------------------------------
__global__ __launch_bounds__(256) void cbn32_kernel(const float* __restrict__ cbs,
                                                    float* __restrict__ cbn32) {
  int row = blockIdx.x * 256 + threadIdx.x;
  if (row >= NB * S) return;
  const float4* r4 = reinterpret_cast<const float4*>(cbs + (size_t)row * CD);
  double s = 0.0;
  for (int q = 0; q < 32; ++q) {
    float4 v = r4[q];
    s += (double)v.x * v.x + (double)v.y * v.y + (double)v.z * v.z + (double)v.w * v.w;
  }
  cbn32[row] = (float)s;
}

__global__ __launch_bounds__(256) void cb16_kernel(const float* __restrict__ cbs,
                                                   unsigned short* __restrict__ cb16) {
  int i = blockIdx.x * 256 + threadIdx.x;
  if (i < NB * S * CD) cb16[i] = f2bf(cbs[i]);
}

__global__ __launch_bounds__(256) void p64t_kernel(const float* __restrict__ Win,
                                                   const float* __restrict__ Wout,
                                                   double* __restrict__ P64t) {
  int n = blockIdx.x * 256 + threadIdx.x;   // 16384
  int k = n >> 7, d = n & 127;
  double s = 0.0;
  for (int D = 0; D < DIN; ++D)
    s = fma((double)Win[(size_t)d * DIN + D], (double)Wout[(size_t)D * CD + k], s);
  P64t[(size_t)k * CD + d] = s;
}

__global__ void cvec64_kernel(const float* __restrict__ Win,
                              const float* __restrict__ bout,
                              double* __restrict__ cvec64) {
  int d = threadIdx.x;  // 128
  double s = 0.0;
  for (int D = 0; D < DIN; ++D)
    s = fma((double)Win[(size_t)d * DIN + D], (double)bout[D], s);
  cvec64[d] = s;
}

// PCF32[book][s][d] = fl32( sum_k cb[book][s][k] * P64t[k][d] + cvec64[d] )
__global__ void pcf_kernel(const float* __restrict__ cbs,
                           const double* __restrict__ P64t,
                           const double* __restrict__ cvec64,
                           float* __restrict__ PCF32) {
  const int s = blockIdx.x, book = blockIdx.y;
  const int d = threadIdx.x;   // 128
  const float* cr = cbs + ((size_t)book * S + s) * CD;
  double acc = 0.0;
  for (int k = 0; k < CD; ++k)
    acc = fma((double)cr[k], P64t[(size_t)k * CD + d], acc);
  PCF32[((size_t)book * S + s) * CD + d] = (float)(acc + cvec64[d]);
}

// WinT[D][d] = Win[d][D]
__global__ __launch_bounds__(256) void winT_kernel(const float* __restrict__ Win,
                                                   float* __restrict__ WinT) {
  int i = blockIdx.x * 256 + threadIdx.x;   // 65536
  int D = i >> 7, d = i & 127;
  WinT[(size_t)D * 128 + d] = Win[(size_t)d * 512 + D];
}

// WoutT[k][D] = Wout[D][k]
__global__ __launch_bounds__(256) void woutT_kernel(const float* __restrict__ Wout,
                                                    float* __restrict__ WoutT) {
  int i = blockIdx.x * 256 + threadIdx.x;   // 65536
  int k = i >> 9, D = i & 511;
  WoutT[(size_t)k * 512 + D] = Wout[(size_t)D * 128 + k];
}

// ---------------------------------------------------------------------------
// Acur[d][tok] = fp32( sum_D Win[d,D]*z[b,D,t] + bin[d] )
__global__ __launch_bounds__(256) void a32_kernel(const float* __restrict__ z,
                                                  const float* __restrict__ WinT,
                                                  const float* __restrict__ bin,
                                                  float* __restrict__ Acur) {
  __shared__ __align__(16) float Al[32][132];
  __shared__ __align__(16) float Bl[32][68];
  const int tid = threadIdx.x;
  const int t0 = blockIdx.x * 64;
  const int b  = blockIdx.y;
  const int mx = tid & 15, nx = tid >> 4;
  float acc[8][4] = {};
  for (int kc = 0; kc < 16; ++kc) {
    __syncthreads();
#pragma unroll
    for (int rep = 0; rep < 4; ++rep) {
      int idx = rep * 256 + tid;
      int kk = idx >> 5, q = idx & 31;
      float4 v = *reinterpret_cast<const float4*>(WinT + (size_t)(kc * 32 + kk) * 128 + q * 4);
      *reinterpret_cast<float4*>(&Al[kk][q * 4]) = v;
    }
#pragma unroll
    for (int rep = 0; rep < 2; ++rep) {
      int idx = rep * 256 + tid;
      int kk = idx >> 4, q = idx & 15;
      float4 v = reinterpret_cast<const float4*>(z + ((size_t)(b * DIN + kc * 32 + kk)) * T + t0)[q];
      *reinterpret_cast<float4*>(&Bl[kk][q * 4]) = v;
    }
    __syncthreads();
#pragma unroll
    for (int kk = 0; kk < 32; ++kk) {
      float4 a0 = *reinterpret_cast<const float4*>(&Al[kk][mx * 8]);
      float4 a1 = *reinterpret_cast<const float4*>(&Al[kk][mx * 8 + 4]);
      float4 bv = *reinterpret_cast<const float4*>(&Bl[kk][nx * 4]);
      float a[8] = {a0.x, a0.y, a0.z, a0.w, a1.x, a1.y, a1.z, a1.w};
      float bb[4] = {bv.x, bv.y, bv.z, bv.w};
#pragma unroll
      for (int u = 0; u < 8; ++u)
#pragma unroll
        for (int j = 0; j < 4; ++j) acc[u][j] = fmaf(a[u], bb[j], acc[u][j]);
    }
  }
#pragma unroll
  for (int u = 0; u < 8; ++u) {
    int d = mx * 8 + u;
    float bi = bin[d];
    size_t base = (size_t)d * NTOK + (size_t)b * T + t0 + nx * 4;
    float4 o = make_float4(acc[u][0] + bi, acc[u][1] + bi, acc[u][2] + bi, acc[u][3] + bi);
    *reinterpret_cast<float4*>(Acur + base) = o;
  }
}

// ---------------------------------------------------------------------------
// FUSED per-book kernel v5 (= v4 with the epilogue Zl buffer DELETED):
//  - epilogue (znp, candidate dots, overflow scan, advance) reads Acur
//    directly (same fp32 values, same order => bitwise-identical results);
//    the block's 32 KB tile is L2-hot from the ZtT stage
//  - LDS ~33 KB => 4-5 blocks/CU
template <bool LAST>
__global__ __launch_bounds__(256) void fused_kernel(
    float* __restrict__ Acur,
    const unsigned short* __restrict__ cb16b,
    const float* __restrict__ cbb,
    const float* __restrict__ cbn32b,
    const float* __restrict__ PCFb,
    int* __restrict__ codes,
    double* __restrict__ lpartF,
    int book) {
  __shared__ __align__(16) unsigned short ZtT[64][152];  // 19.5 KB (pad 152)
  __shared__ float Cna[1024];
  __shared__ unsigned int gminU[64];
  __shared__ int   fcnt[64];
  __shared__ unsigned short fls[64][FCAP];
  __shared__ double znp[4][64];
  __shared__ float znl[64];
  __shared__ float bestv[4][64];    // aliased as rm[256] in overflow loop
  __shared__ int   bests[4][64];    // aliased as ri[256] in overflow loop
  __shared__ int   ovl[64];
  __shared__ unsigned char ovf[64];
  __shared__ double lred[64];
  __shared__ int   scode[64];
  __shared__ int   ovn;

  const int tid = threadIdx.x;
  const int tok0 = blockIdx.x * 64;
  const int wv = tid >> 6, ln = tid & 63;
  const int lr = ln & 15, lg = ln >> 4;

  // stage ZtT[t][k] = f2bf(Acur[k][tok0+t])
  for (int rep = 0; rep < 8; ++rep) {
    int idx = rep * 256 + tid;
    int k = idx >> 4, qq = idx & 15;
    float4 v = *reinterpret_cast<const float4*>(Acur + (size_t)k * NTOK + tok0 + qq * 4);
    ZtT[qq * 4 + 0][k] = f2bf(v.x);
    ZtT[qq * 4 + 1][k] = f2bf(v.y);
    ZtT[qq * 4 + 2][k] = f2bf(v.z);
    ZtT[qq * 4 + 3][k] = f2bf(v.w);
  }
#pragma unroll
  for (int rep = 0; rep < 4; ++rep) Cna[rep * 256 + tid] = cbn32b[rep * 256 + tid];
  if (tid < 64) { gminU[tid] = 0xFFFFFFFFu; fcnt[tid] = 0; }
  __syncthreads();

  // ======== PASS A: barrier-free; fold mins into gminU via atomicMin ========
  for (int c = 0; c < 8; ++c) {
    f32x4 acc[2][4];
#pragma unroll
    for (int ss = 0; ss < 2; ++ss)
#pragma unroll
      for (int ts = 0; ts < 4; ++ts) acc[ss][ts] = (f32x4){0.f, 0.f, 0.f, 0.f};
#pragma unroll
    for (int ks = 0; ks < 4; ++ks) {
      const unsigned short* ar =
          cb16b + (size_t)(c * 128 + wv * 32 + lr) * 128 + ks * 32 + lg * 8;
      bf16x8 a0 = *reinterpret_cast<const bf16x8*>(ar);
      bf16x8 a1 = *reinterpret_cast<const bf16x8*>(ar + 16 * 128);
      bf16x8 b0 = *reinterpret_cast<const bf16x8*>(&ZtT[lr][ks * 32 + lg * 8]);
      bf16x8 b1 = *reinterpret_cast<const bf16x8*>(&ZtT[16 + lr][ks * 32 + lg * 8]);
      bf16x8 b2 = *reinterpret_cast<const bf16x8*>(&ZtT[32 + lr][ks * 32 + lg * 8]);
      bf16x8 b3 = *reinterpret_cast<const bf16x8*>(&ZtT[48 + lr][ks * 32 + lg * 8]);
      acc[0][0] = __builtin_amdgcn_mfma_f32_16x16x32_bf16(a0, b0, acc[0][0], 0, 0, 0);
      acc[0][1] = __builtin_amdgcn_mfma_f32_16x16x32_bf16(a0, b1, acc[0][1], 0, 0, 0);
      acc[0][2] = __builtin_amdgcn_mfma_f32_16x16x32_bf16(a0, b2, acc[0][2], 0, 0, 0);
      acc[0][3] = __builtin_amdgcn_mfma_f32_16x16x32_bf16(a0, b3, acc[0][3], 0, 0, 0);
      acc[1][0] = __builtin_amdgcn_mfma_f32_16x16x32_bf16(a1, b0, acc[1][0], 0, 0, 0);
      acc[1][1] = __builtin_amdgcn_mfma_f32_16x16x32_bf16(a1, b1, acc[1][1], 0, 0, 0);
      acc[1][2] = __builtin_amdgcn_mfma_f32_16x16x32_bf16(a1, b2, acc[1][2], 0, 0, 0);
      acc[1][3] = __builtin_amdgcn_mfma_f32_16x16x32_bf16(a1, b3, acc[1][3], 0, 0, 0);
    }
#pragma unroll
    for (int ss = 0; ss < 2; ++ss)
#pragma unroll
      for (int ts = 0; ts < 4; ++ts)
#pragma unroll
        for (int r = 0; r < 4; ++r)
          acc[ss][ts][r] = fmaf(-2.f, acc[ss][ts][r],
                                Cna[c * 128 + wv * 32 + ss * 16 + lg * 4 + r]);
#pragma unroll
    for (int ts = 0; ts < 4; ++ts) {
      float m = acc[0][ts][0];
#pragma unroll
      for (int r = 1; r < 4; ++r) m = fminf(m, acc[0][ts][r]);
#pragma unroll
      for (int r = 0; r < 4; ++r) m = fminf(m, acc[1][ts][r]);
      m = fminf(m, __shfl_xor(m, 16));
      m = fminf(m, __shfl_xor(m, 32));
      if (lg == 0) atomicMin(&gminU[ts * 16 + lr], fenc(m));
    }
  }
  __syncthreads();

  // ======== PASS B: barrier-free; flag vs FINAL gmin ========
  for (int c = 0; c < 8; ++c) {
    f32x4 acc[2][4];
#pragma unroll
    for (int ss = 0; ss < 2; ++ss)
#pragma unroll
      for (int ts = 0; ts < 4; ++ts) acc[ss][ts] = (f32x4){0.f, 0.f, 0.f, 0.f};
#pragma unroll
    for (int ks = 0; ks < 4; ++ks) {
      const unsigned short* ar =
          cb16b + (size_t)(c * 128 + wv * 32 + lr) * 128 + ks * 32 + lg * 8;
      bf16x8 a0 = *reinterpret_cast<const bf16x8*>(ar);
      bf16x8 a1 = *reinterpret_cast<const bf16x8*>(ar + 16 * 128);
      bf16x8 b0 = *reinterpret_cast<const bf16x8*>(&ZtT[lr][ks * 32 + lg * 8]);
      bf16x8 b1 = *reinterpret_cast<const bf16x8*>(&ZtT[16 + lr][ks * 32 + lg * 8]);
      bf16x8 b2 = *reinterpret_cast<const bf16x8*>(&ZtT[32 + lr][ks * 32 + lg * 8]);
      bf16x8 b3 = *reinterpret_cast<const bf16x8*>(&ZtT[48 + lr][ks * 32 + lg * 8]);
      acc[0][0] = __builtin_amdgcn_mfma_f32_16x16x32_bf16(a0, b0, acc[0][0], 0, 0, 0);
      acc[0][1] = __builtin_amdgcn_mfma_f32_16x16x32_bf16(a0, b1, acc[0][1], 0, 0, 0);
      acc[0][2] = __builtin_amdgcn_mfma_f32_16x16x32_bf16(a0, b2, acc[0][2], 0, 0, 0);
      acc[0][3] = __builtin_amdgcn_mfma_f32_16x16x32_bf16(a0, b3, acc[0][3], 0, 0, 0);
      acc[1][0] = __builtin_amdgcn_mfma_f32_16x16x32_bf16(a1, b0, acc[1][0], 0, 0, 0);
      acc[1][1] = __builtin_amdgcn_mfma_f32_16x16x32_bf16(a1, b1, acc[1][1], 0, 0, 0);
      acc[1][2] = __builtin_amdgcn_mfma_f32_16x16x32_bf16(a1, b2, acc[1][2], 0, 0, 0);
      acc[1][3] = __builtin_amdgcn_mfma_f32_16x16x32_bf16(a1, b3, acc[1][3], 0, 0, 0);
    }
#pragma unroll
    for (int ss = 0; ss < 2; ++ss)
#pragma unroll
      for (int ts = 0; ts < 4; ++ts)
#pragma unroll
        for (int r = 0; r < 4; ++r)
          acc[ss][ts][r] = fmaf(-2.f, acc[ss][ts][r],
                                Cna[c * 128 + wv * 32 + ss * 16 + lg * 4 + r]);
#pragma unroll
    for (int ts = 0; ts < 4; ++ts) {
      int t = ts * 16 + lr;
      float thr = fdec(gminU[t]) + MARGIN;
#pragma unroll
      for (int ss = 0; ss < 2; ++ss)
#pragma unroll
        for (int r = 0; r < 4; ++r) {
          float v = acc[ss][ts][r];
          if (v <= thr) {
            int s = c * 128 + wv * 32 + ss * 16 + lg * 4 + r;
            int pos = atomicAdd(&fcnt[t], 1);
            if (pos < FCAP) fls[t][pos] = (unsigned short)s;
          }
        }
    }
  }
  __syncthreads();

  // ======== EPILOGUE: exact evaluation (bitwise round-6 numerics),
  //          z read directly from Acur (L2-hot tile) ========
  float* rm = &bestv[0][0];                                     // alias
  int*   ri = &bests[0][0];

  const int b = tok0 >> 12;
  const int tl = tid & 63, h = tid >> 6;
  if (tid == 0) ovn = 0;
  {
    double s = 0.0;
#pragma unroll
    for (int dd = 0; dd < 32; ++dd) {
      double v = (double)Acur[(size_t)(h * 32 + dd) * NTOK + tok0 + tl];
      s += v * v;
    }
    znp[h][tl] = s;
  }
  __syncthreads();
  if (tid < 64) znl[tid] = (float)(((znp[0][tid] + znp[1][tid]) + znp[2][tid]) + znp[3][tid]);
  __syncthreads();
  const float zn = znl[tl];
  const int tok = tok0 + tl;
  const int cnt = fcnt[tl];
  float bm = 3.4e38f; int bi = 0x7fffffff;
  if (cnt <= FCAP) {
    if (h == 0) ovf[tl] = 0;
    for (int i = h; i < cnt; i += 4) {
      int s = fls[tl][i];
      const float* cr = cbb + (size_t)s * CD;
      double e = 0.0;
      for (int d = 0; d < CD; ++d)
        e = fma((double)cr[d], (double)Acur[(size_t)d * NTOK + tok], e);
      float M = (float)e;
      float d2 = __fadd_rn(__fsub_rn(zn, __fmul_rn(2.f, M)), Cna[s]);
      if (d2 < bm || (d2 == bm && s < bi)) { bm = d2; bi = s; }
    }
  } else {
    if (h == 0) { int p = atomicAdd(&ovn, 1); ovl[p] = tl; ovf[tl] = 1; }
  }
  bestv[h][tl] = bm; bests[h][tl] = bi;
  __syncthreads();
  if (tid < 64 && !ovf[tid]) {
    float fv = bestv[0][tid]; int fs = bests[0][tid];
#pragma unroll
    for (int x = 1; x < 4; ++x) {
      float v = bestv[x][tid]; int s = bests[x][tid];
      if (v < fv || (v == fv && s < fs)) { fv = v; fs = s; }
    }
    codes[((size_t)b * NB + book) * T + ((tok0 + tid) & (T - 1))] = fs;
    scode[tid] = fs;
    lred[tid] = (double)fv;
  }
  __syncthreads();
  const int no = ovn;
  for (int e = 0; e < no; ++e) {
    const int tt = ovl[e];
    const float zn2 = znl[tt];
    double e0 = 0.0, e1 = 0.0, e2 = 0.0, e3 = 0.0;
    const float* c0 = cbb + (size_t)(tid      ) * CD;
    const float* c1 = cbb + (size_t)(tid + 256) * CD;
    const float* c2 = cbb + (size_t)(tid + 512) * CD;
    const float* c3 = cbb + (size_t)(tid + 768) * CD;
    for (int d = 0; d < CD; ++d) {
      double zv = (double)Acur[(size_t)d * NTOK + tok0 + tt];
      e0 = fma((double)c0[d], zv, e0);
      e1 = fma((double)c1[d], zv, e1);
      e2 = fma((double)c2[d], zv, e2);
      e3 = fma((double)c3[d], zv, e3);
    }
    float bm2 = 3.4e38f; int bi2 = 0x7fffffff;
    {
      float d2;
      d2 = __fadd_rn(__fsub_rn(zn2, __fmul_rn(2.f, (float)e0)), Cna[tid]);
      if (d2 < bm2) { bm2 = d2; bi2 = tid; }
      d2 = __fadd_rn(__fsub_rn(zn2, __fmul_rn(2.f, (float)e1)), Cna[tid + 256]);
      if (d2 < bm2) { bm2 = d2; bi2 = tid + 256; }
      d2 = __fadd_rn(__fsub_rn(zn2, __fmul_rn(2.f, (float)e2)), Cna[tid + 512]);
      if (d2 < bm2) { bm2 = d2; bi2 = tid + 512; }
      d2 = __fadd_rn(__fsub_rn(zn2, __fmul_rn(2.f, (float)e3)), Cna[tid + 768]);
      if (d2 < bm2) { bm2 = d2; bi2 = tid + 768; }
    }
    rm[tid] = bm2; ri[tid] = bi2;
    __syncthreads();
    for (int off = 128; off; off >>= 1) {
      if (tid < off) {
        float om = rm[tid + off]; int oi = ri[tid + off];
        if (om < rm[tid] || (om == rm[tid] && oi < ri[tid])) { rm[tid] = om; ri[tid] = oi; }
      }
      __syncthreads();
    }
    if (tid == 0) {
      codes[((size_t)b * NB + book) * T + ((tok0 + tt) & (T - 1))] = ri[0];
      scode[tt] = ri[0];
      lred[tt] = (double)rm[0];
    }
    __syncthreads();
  }
  if (tid == 0) {
    double sum = 0.0;
    for (int i = 0; i < 64; ++i) sum += lred[i];
    lpartF[(size_t)book * 1024 + blockIdx.x] = sum;
  }

  // ======== ADVANCE (books 0..6): Acur -= PCF[code] (RMW, own columns) ====
  if constexpr (!LAST) {
    __syncthreads();
    const int code = scode[tl];
    const float* pr = PCFb + (size_t)code * CD + h * 32;
#pragma unroll
    for (int d = 0; d < 32; ++d) {
      size_t idx = (size_t)(h * 32 + d) * NTOK + tok0 + tl;
      Acur[idx] = Acur[idx] - pr[d];
    }
  }
}

// ---------------------------------------------------------------------------
// qs32[k][tok] = sum_books cb[book][code_book(tok)][k]   (fp32, z_q only)
__global__ __launch_bounds__(256) void qsgather_kernel(const float* __restrict__ cbs,
                                                       const int* __restrict__ codes,
                                                       float* __restrict__ qs32) {
  __shared__ int cds[64][8];
  const int tid = threadIdx.x;
  const int tok0 = blockIdx.x * 64;
  const int tl = tid & 63, h = tid >> 6;
  if (tid < 64) {
    int tok = tok0 + tid, b = tok >> 12, t = tok & (T - 1);
#pragma unroll
    for (int book = 0; book < NB; ++book)
      cds[tid][book] = codes[((size_t)b * NB + book) * T + t];
  }
  __syncthreads();
  const int tok = tok0 + tl;
  float acc[32] = {};
#pragma unroll
  for (int book = 0; book < NB; ++book) {
    const float* cr = cbs + ((size_t)book * S + cds[tl][book]) * CD + h * 32;
#pragma unroll
    for (int k = 0; k < 32; ++k) acc[k] += cr[k];
  }
#pragma unroll
  for (int k = 0; k < 32; ++k)
    qs32[(size_t)(h * 32 + k) * NTOK + tok] = acc[k];
}

// ---------------------------------------------------------------------------
// z_q (fp32, 2% tolerance)
__global__ __launch_bounds__(256) void final32_kernel(const float* __restrict__ qs32,
                                                      const float* __restrict__ WoutT,
                                                      const float* __restrict__ bout,
                                                      float* __restrict__ out) {
  __shared__ __align__(16) float Al[32][132];
  __shared__ __align__(16) float Bl[32][68];
  const int tid = threadIdx.x;
  const int t0 = blockIdx.x * 64;
  const int Dg = blockIdx.y;
  const int b  = blockIdx.z;
  const int mx = tid & 15, nx = tid >> 4;
  const size_t tokbase = (size_t)b * T + t0;
  float acc[8][4] = {};
  for (int kc = 0; kc < 4; ++kc) {
    __syncthreads();
#pragma unroll
    for (int rep = 0; rep < 4; ++rep) {
      int idx = rep * 256 + tid;
      int kk = idx >> 5, q = idx & 31;
      float4 v = *reinterpret_cast<const float4*>(
          WoutT + (size_t)(kc * 32 + kk) * 512 + Dg * 128 + q * 4);
      *reinterpret_cast<float4*>(&Al[kk][q * 4]) = v;
    }
#pragma unroll
    for (int rep = 0; rep < 2; ++rep) {
      int idx = rep * 256 + tid;
      int kk = idx >> 4, q = idx & 15;
      *reinterpret_cast<float4*>(&Bl[kk][q * 4]) =
          *reinterpret_cast<const float4*>(qs32 + (size_t)(kc * 32 + kk) * NTOK + tokbase + q * 4);
    }
    __syncthreads();
#pragma unroll
    for (int kk = 0; kk < 32; ++kk) {
      float4 a0 = *reinterpret_cast<const float4*>(&Al[kk][mx * 8]);
      float4 a1 = *reinterpret_cast<const float4*>(&Al[kk][mx * 8 + 4]);
      float4 bv = *reinterpret_cast<const float4*>(&Bl[kk][nx * 4]);
      float a[8] = {a0.x, a0.y, a0.z, a0.w, a1.x, a1.y, a1.z, a1.w};
      float bb[4] = {bv.x, bv.y, bv.z, bv.w};
#pragma unroll
      for (int u = 0; u < 8; ++u)
#pragma unroll
        for (int j = 0; j < 4; ++j) acc[u][j] = fmaf(a[u], bb[j], acc[u][j]);
    }
  }
#pragma unroll
  for (int u = 0; u < 8; ++u) {
    int D = Dg * 128 + mx * 8 + u;
    float bo = 8.0f * bout[D];
    float4 o = make_float4(acc[u][0] + bo, acc[u][1] + bo, acc[u][2] + bo, acc[u][3] + bo);
    reinterpret_cast<float4*>(out + ((size_t)b * DIN + D) * T + t0)[nx] = o;
  }
}

// ---------------------------------------------------------------------------
__global__ __launch_bounds__(256) void codes_out_kernel(const int* __restrict__ codes,
                                                        float* __restrict__ out) {
  int k = blockIdx.x * 256 + threadIdx.x;
  if (k < BATCH * NB * T)
    out[(size_t)BATCH * DIN * T + k] = (float)codes[k];
}

__global__ __launch_bounds__(256) void loss_out_kernel(const double* __restrict__ lpF,
                                                       float* __restrict__ out) {
  __shared__ double red[256];
  double s = 0.0;
  for (int i = threadIdx.x; i < NB * 1024; i += 256) s += lpF[i];
  red[threadIdx.x] = s;
  __syncthreads();
  for (int off = 128; off; off >>= 1) {
    if (threadIdx.x < off) red[threadIdx.x] += red[threadIdx.x + off];
    __syncthreads();
  }
  if (threadIdx.x == 0)
    out[(size_t)BATCH * DIN * T + (size_t)BATCH * NB * T] =
        (float)(red[0] * 1.25 / 8388608.0);
}

// ---------------------------------------------------------------------------
extern "C" void kernel_launch(void* const* d_in, const int* in_sizes, int n_in,
                              void* d_out, int out_size, void* d_ws, size_t ws_size,
                              hipStream_t stream) {
  (void)in_sizes; (void)n_in; (void)out_size; (void)ws_size;
  const float* z    = (const float*)d_in[0];
  const float* Win  = (const float*)d_in[1];
  const float* bin  = (const float*)d_in[2];
  const float* Wout = (const float*)d_in[3];
  const float* bout = (const float*)d_in[4];
  const float* cbs  = (const float*)d_in[5];
  float* out = (float*)d_out;
  float* Acur = out;   // fp32 running z_proj [d][tok] (33.6MB), aliases z_q region

  char* w = (char*)d_ws;
  double* P64t  = (double*)w;  w += (size_t)CD * CD * 8;
  double* cvec64= (double*)w;  w += CD * 8;
  double* lpartF= (double*)w;  w += (size_t)NB * 1024 * 8;
  float*  PCF32 = (float*)w;   w += (size_t)NB * S * CD * 4;      // 4.2 MB
  float*  qs32  = (float*)w;   w += (size_t)CD * NTOK * 4;        // 33.6 MB
  float*  cbn32 = (float*)w;   w += (size_t)NB * S * 4;
  float*  WinT  = (float*)w;   w += (size_t)DIN * CD * 4;         // 256 KB
  float*  WoutT = (float*)w;   w += (size_t)CD * DIN * 4;         // 256 KB
  unsigned short* cb16 = (unsigned short*)w; w += (size_t)NB * S * CD * 2; // 2.1 MB
  int*    codes = (int*)w;     w += (size_t)BATCH * NB * T * 4;

  cbn32_kernel<<<(NB * S + 255) / 256, 256, 0, stream>>>(cbs, cbn32);
  cb16_kernel<<<(NB * S * CD + 255) / 256, 256, 0, stream>>>(cbs, cb16);
  p64t_kernel<<<64, 256, 0, stream>>>(Win, Wout, P64t);
  cvec64_kernel<<<1, 128, 0, stream>>>(Win, bout, cvec64);
  pcf_kernel<<<dim3(S, NB), 128, 0, stream>>>(cbs, P64t, cvec64, PCF32);
  winT_kernel<<<256, 256, 0, stream>>>(Win, WinT);
  woutT_kernel<<<256, 256, 0, stream>>>(Wout, WoutT);
  a32_kernel<<<dim3(T / 64, BATCH), 256, 0, stream>>>(z, WinT, bin, Acur);

  for (int book = 0; book < NB; ++book) {
    const float* cb = cbs + (size_t)book * S * CD;
    const unsigned short* cbh = cb16 + (size_t)book * S * CD;
    if (book < NB - 1)
      fused_kernel<false><<<NTOK / 64, 256, 0, stream>>>(
          Acur, cbh, cb, cbn32 + book * S,
          PCF32 + (size_t)book * S * CD, codes, lpartF, book);
    else
      fused_kernel<true><<<NTOK / 64, 256, 0, stream>>>(
          Acur, cbh, cb, cbn32 + book * S,
          PCF32 + (size_t)book * S * CD, codes, lpartF, book);
  }
  qsgather_kernel<<<NTOK / 64, 256, 0, stream>>>(cbs, codes, qs32);
  final32_kernel<<<dim3(T / 64, DIN / 128, BATCH), 256, 0, stream>>>(qs32, WoutT, bout, out);
  codes_out_kernel<<<(BATCH * NB * T + 255) / 256, 256, 0, stream>>>(codes, out);
  loss_out_kernel<<<1, 256, 0, stream>>>(lpartF, out);
}

// Round 19
// 1161.272 us; speedup vs baseline: 1.1801x; 1.1801x over previous
//
#include <hip/hip_runtime.h>
#include <cstdint>

constexpr int NB   = 8;
constexpr int S    = 1024;
constexpr int CD   = 128;
constexpr int DIN  = 512;
constexpr int BATCH= 16;
constexpr int T    = 4096;
constexpr int NTOK = BATCH * T;        // 65536
constexpr int FCAP = 24;
constexpr float MARGIN = 4e-3f;        // > 2 * 1.3e-3 worst-case bf16 approx error

typedef __attribute__((ext_vector_type(8))) short bf16x8;
typedef __attribute__((ext_vector_type(4))) float f32x4;

__device__ __forceinline__ unsigned short f2bf(float f) {
  unsigned int u = __float_as_uint(f);
  return (unsigned short)((u + 0x7fffu + ((u >> 16) & 1u)) >> 16);
}
// order-preserving float<->uint for atomicMin (finite values)
__device__ __forceinline__ unsigned int fenc(float f) {
  unsigned int u = __float_as_uint(f);
  return (u & 0x80000000u) ? ~u : (u | 0x80000000u);
}
__device__ __forceinline__ float fdec(unsigned int e) {
  return (e & 0x80000000u) ? __uint_as_float(e ^ 0x80000000u) : __uint_as_float(~e);
}

// ---------------------------------------------------------------------------
__global__ __launch_bounds__(256) void cbn32_kernel(const float* __restrict__ cbs,
                                                    float* __restrict__ cbn32) {
  int row = blockIdx.x * 256 + threadIdx.x;
  if (row >= NB * S) return;
  const float4* r4 = reinterpret_cast<const float4*>(cbs + (size_t)row * CD);
  double s = 0.0;
  for (int q = 0; q < 32; ++q) {
    float4 v = r4[q];
    s += (double)v.x * v.x + (double)v.y * v.y + (double)v.z * v.z + (double)v.w * v.w;
  }
  cbn32[row] = (float)s;
}

__global__ __launch_bounds__(256) void cb16_kernel(const float* __restrict__ cbs,
                                                   unsigned short* __restrict__ cb16) {
  int i = blockIdx.x * 256 + threadIdx.x;
  if (i < NB * S * CD) cb16[i] = f2bf(cbs[i]);
}

__global__ __launch_bounds__(256) void p64t_kernel(const float* __restrict__ Win,
                                                   const float* __restrict__ Wout,
                                                   double* __restrict__ P64t) {
  int n = blockIdx.x * 256 + threadIdx.x;   // 16384
  int k = n >> 7, d = n & 127;
  double s = 0.0;
  for (int D = 0; D < DIN; ++D)
    s = fma((double)Win[(size_t)d * DIN + D], (double)Wout[(size_t)D * CD + k], s);
  P64t[(size_t)k * CD + d] = s;
}

__global__ void cvec64_kernel(const float* __restrict__ Win,
                              const float* __restrict__ bout,
                              double* __restrict__ cvec64) {
  int d = threadIdx.x;  // 128
  double s = 0.0;
  for (int D = 0; D < DIN; ++D)
    s = fma((double)Win[(size_t)d * DIN + D], (double)bout[D], s);
  cvec64[d] = s;
}

// PCF32[book][s][d] = fl32( sum_k cb[book][s][k] * P64t[k][d] + cvec64[d] )
__global__ void pcf_kernel(const float* __restrict__ cbs,
                           const double* __restrict__ P64t,
                           const double* __restrict__ cvec64,
                           float* __restrict__ PCF32) {
  const int s = blockIdx.x, book = blockIdx.y;
  const int d = threadIdx.x;   // 128
  const float* cr = cbs + ((size_t)book * S + s) * CD;
  double acc = 0.0;
  for (int k = 0; k < CD; ++k)
    acc = fma((double)cr[k], P64t[(size_t)k * CD + d], acc);
  PCF32[((size_t)book * S + s) * CD + d] = (float)(acc + cvec64[d]);
}

// WinT[D][d] = Win[d][D]
__global__ __launch_bounds__(256) void winT_kernel(const float* __restrict__ Win,
                                                   float* __restrict__ WinT) {
  int i = blockIdx.x * 256 + threadIdx.x;   // 65536
  int D = i >> 7, d = i & 127;
  WinT[(size_t)D * 128 + d] = Win[(size_t)d * 512 + D];
}

// WoutT[k][D] = Wout[D][k]
__global__ __launch_bounds__(256) void woutT_kernel(const float* __restrict__ Wout,
                                                    float* __restrict__ WoutT) {
  int i = blockIdx.x * 256 + threadIdx.x;   // 65536
  int k = i >> 9, D = i & 511;
  WoutT[(size_t)k * 512 + D] = Wout[(size_t)D * 128 + k];
}

// ---------------------------------------------------------------------------
// Acur[d][tok] = fp32( sum_D Win[d,D]*z[b,D,t] + bin[d] )
__global__ __launch_bounds__(256) void a32_kernel(const float* __restrict__ z,
                                                  const float* __restrict__ WinT,
                                                  const float* __restrict__ bin,
                                                  float* __restrict__ Acur) {
  __shared__ __align__(16) float Al[32][132];
  __shared__ __align__(16) float Bl[32][68];
  const int tid = threadIdx.x;
  const int t0 = blockIdx.x * 64;
  const int b  = blockIdx.y;
  const int mx = tid & 15, nx = tid >> 4;
  float acc[8][4] = {};
  for (int kc = 0; kc < 16; ++kc) {
    __syncthreads();
#pragma unroll
    for (int rep = 0; rep < 4; ++rep) {
      int idx = rep * 256 + tid;
      int kk = idx >> 5, q = idx & 31;
      float4 v = *reinterpret_cast<const float4*>(WinT + (size_t)(kc * 32 + kk) * 128 + q * 4);
      *reinterpret_cast<float4*>(&Al[kk][q * 4]) = v;
    }
#pragma unroll
    for (int rep = 0; rep < 2; ++rep) {
      int idx = rep * 256 + tid;
      int kk = idx >> 4, q = idx & 15;
      float4 v = reinterpret_cast<const float4*>(z + ((size_t)(b * DIN + kc * 32 + kk)) * T + t0)[q];
      *reinterpret_cast<float4*>(&Bl[kk][q * 4]) = v;
    }
    __syncthreads();
#pragma unroll
    for (int kk = 0; kk < 32; ++kk) {
      float4 a0 = *reinterpret_cast<const float4*>(&Al[kk][mx * 8]);
      float4 a1 = *reinterpret_cast<const float4*>(&Al[kk][mx * 8 + 4]);
      float4 bv = *reinterpret_cast<const float4*>(&Bl[kk][nx * 4]);
      float a[8] = {a0.x, a0.y, a0.z, a0.w, a1.x, a1.y, a1.z, a1.w};
      float bb[4] = {bv.x, bv.y, bv.z, bv.w};
#pragma unroll
      for (int u = 0; u < 8; ++u)
#pragma unroll
        for (int j = 0; j < 4; ++j) acc[u][j] = fmaf(a[u], bb[j], acc[u][j]);
    }
  }
#pragma unroll
  for (int u = 0; u < 8; ++u) {
    int d = mx * 8 + u;
    float bi = bin[d];
    size_t base = (size_t)d * NTOK + (size_t)b * T + t0 + nx * 4;
    float4 o = make_float4(acc[u][0] + bi, acc[u][1] + bi, acc[u][2] + bi, acc[u][3] + bi);
    *reinterpret_cast<float4*>(Acur + base) = o;
  }
}

// ---------------------------------------------------------------------------
// FUSED per-book kernel v6 (= v4 base + A-fragment software prefetch):
//  - same arithmetic, same order => codes bitwise identical to v4
//  - chunk c+1's cb16 loads are issued before chunk c's MFMA consumes,
//    breaking the per-wave serial L2-latency chain
template <bool LAST>
__global__ __launch_bounds__(256) void fused_kernel(
    float* __restrict__ Acur,
    const unsigned short* __restrict__ cb16b,
    const float* __restrict__ cbb,
    const float* __restrict__ cbn32b,
    const float* __restrict__ PCFb,
    int* __restrict__ codes,
    double* __restrict__ lpartF,
    int book) {
  __shared__ __align__(16) unsigned char smemU[32768]; // ZtT (scoring) | Zl (epilogue)
  __shared__ float Cna[1024];
  __shared__ unsigned int gminU[64];
  __shared__ int   fcnt[64];
  __shared__ unsigned short fls[64][FCAP];
  __shared__ double znp[4][64];
  __shared__ float znl[64];
  __shared__ float bestv[4][64];    // aliased as rm[256] in overflow loop
  __shared__ int   bests[4][64];    // aliased as ri[256] in overflow loop
  __shared__ int   ovl[64];
  __shared__ unsigned char ovf[64];
  __shared__ double lred[64];
  __shared__ int   scode[64];
  __shared__ int   ovn;

  auto ZtT = reinterpret_cast<unsigned short(*)[152]>(smemU);  // 64 x 152 (pad)

  const int tid = threadIdx.x;
  const int tok0 = blockIdx.x * 64;
  const int wv = tid >> 6, ln = tid & 63;
  const int lr = ln & 15, lg = ln >> 4;

  // per-wave base for A-fragment loads
  const unsigned short* abase = cb16b + (size_t)(wv * 32 + lr) * 128 + lg * 8;

  // stage ZtT[t][k] = f2bf(Acur[k][tok0+t])
  for (int rep = 0; rep < 8; ++rep) {
    int idx = rep * 256 + tid;
    int k = idx >> 4, qq = idx & 15;
    float4 v = *reinterpret_cast<const float4*>(Acur + (size_t)k * NTOK + tok0 + qq * 4);
    ZtT[qq * 4 + 0][k] = f2bf(v.x);
    ZtT[qq * 4 + 1][k] = f2bf(v.y);
    ZtT[qq * 4 + 2][k] = f2bf(v.z);
    ZtT[qq * 4 + 3][k] = f2bf(v.w);
  }
#pragma unroll
  for (int rep = 0; rep < 4; ++rep) Cna[rep * 256 + tid] = cbn32b[rep * 256 + tid];
  if (tid < 64) { gminU[tid] = 0xFFFFFFFFu; fcnt[tid] = 0; }
  __syncthreads();

  // ======== PASS A: barrier-free; prefetched A-frags; atomicMin gmin ========
  {
    bf16x8 pa[8];
#pragma unroll
    for (int ks = 0; ks < 4; ++ks) {
      pa[ks * 2 + 0] = *reinterpret_cast<const bf16x8*>(abase + (size_t)ks * 32);
      pa[ks * 2 + 1] = *reinterpret_cast<const bf16x8*>(abase + 16 * 128 + (size_t)ks * 32);
    }
    for (int c = 0; c < 8; ++c) {
      bf16x8 ca[8];
#pragma unroll
      for (int i = 0; i < 8; ++i) ca[i] = pa[i];
      if (c < 7) {
        const unsigned short* nb = abase + (size_t)(c + 1) * 128 * 128;
#pragma unroll
        for (int ks = 0; ks < 4; ++ks) {
          pa[ks * 2 + 0] = *reinterpret_cast<const bf16x8*>(nb + (size_t)ks * 32);
          pa[ks * 2 + 1] = *reinterpret_cast<const bf16x8*>(nb + 16 * 128 + (size_t)ks * 32);
        }
      }
      f32x4 acc[2][4];
#pragma unroll
      for (int ss = 0; ss < 2; ++ss)
#pragma unroll
        for (int ts = 0; ts < 4; ++ts) acc[ss][ts] = (f32x4){0.f, 0.f, 0.f, 0.f};
#pragma unroll
      for (int ks = 0; ks < 4; ++ks) {
        bf16x8 b0 = *reinterpret_cast<const bf16x8*>(&ZtT[lr][ks * 32 + lg * 8]);
        bf16x8 b1 = *reinterpret_cast<const bf16x8*>(&ZtT[16 + lr][ks * 32 + lg * 8]);
        bf16x8 b2 = *reinterpret_cast<const bf16x8*>(&ZtT[32 + lr][ks * 32 + lg * 8]);
        bf16x8 b3 = *reinterpret_cast<const bf16x8*>(&ZtT[48 + lr][ks * 32 + lg * 8]);
        acc[0][0] = __builtin_amdgcn_mfma_f32_16x16x32_bf16(ca[ks*2+0], b0, acc[0][0], 0, 0, 0);
        acc[0][1] = __builtin_amdgcn_mfma_f32_16x16x32_bf16(ca[ks*2+0], b1, acc[0][1], 0, 0, 0);
        acc[0][2] = __builtin_amdgcn_mfma_f32_16x16x32_bf16(ca[ks*2+0], b2, acc[0][2], 0, 0, 0);
        acc[0][3] = __builtin_amdgcn_mfma_f32_16x16x32_bf16(ca[ks*2+0], b3, acc[0][3], 0, 0, 0);
        acc[1][0] = __builtin_amdgcn_mfma_f32_16x16x32_bf16(ca[ks*2+1], b0, acc[1][0], 0, 0, 0);
        acc[1][1] = __builtin_amdgcn_mfma_f32_16x16x32_bf16(ca[ks*2+1], b1, acc[1][1], 0, 0, 0);
        acc[1][2] = __builtin_amdgcn_mfma_f32_16x16x32_bf16(ca[ks*2+1], b2, acc[1][2], 0, 0, 0);
        acc[1][3] = __builtin_amdgcn_mfma_f32_16x16x32_bf16(ca[ks*2+1], b3, acc[1][3], 0, 0, 0);
      }
#pragma unroll
      for (int ss = 0; ss < 2; ++ss)
#pragma unroll
        for (int ts = 0; ts < 4; ++ts)
#pragma unroll
          for (int r = 0; r < 4; ++r)
            acc[ss][ts][r] = fmaf(-2.f, acc[ss][ts][r],
                                  Cna[c * 128 + wv * 32 + ss * 16 + lg * 4 + r]);
#pragma unroll
      for (int ts = 0; ts < 4; ++ts) {
        float m = acc[0][ts][0];
#pragma unroll
        for (int r = 1; r < 4; ++r) m = fminf(m, acc[0][ts][r]);
#pragma unroll
        for (int r = 0; r < 4; ++r) m = fminf(m, acc[1][ts][r]);
        m = fminf(m, __shfl_xor(m, 16));
        m = fminf(m, __shfl_xor(m, 32));
        if (lg == 0) atomicMin(&gminU[ts * 16 + lr], fenc(m));
      }
    }
  }
  __syncthreads();

  // ======== PASS B: barrier-free; prefetched; flag vs FINAL gmin ========
  {
    bf16x8 pa[8];
#pragma unroll
    for (int ks = 0; ks < 4; ++ks) {
      pa[ks * 2 + 0] = *reinterpret_cast<const bf16x8*>(abase + (size_t)ks * 32);
      pa[ks * 2 + 1] = *reinterpret_cast<const bf16x8*>(abase + 16 * 128 + (size_t)ks * 32);
    }
    for (int c = 0; c < 8; ++c) {
      bf16x8 ca[8];
#pragma unroll
      for (int i = 0; i < 8; ++i) ca[i] = pa[i];
      if (c < 7) {
        const unsigned short* nb = abase + (size_t)(c + 1) * 128 * 128;
#pragma unroll
        for (int ks = 0; ks < 4; ++ks) {
          pa[ks * 2 + 0] = *reinterpret_cast<const bf16x8*>(nb + (size_t)ks * 32);
          pa[ks * 2 + 1] = *reinterpret_cast<const bf16x8*>(nb + 16 * 128 + (size_t)ks * 32);
        }
      }
      f32x4 acc[2][4];
#pragma unroll
      for (int ss = 0; ss < 2; ++ss)
#pragma unroll
        for (int ts = 0; ts < 4; ++ts) acc[ss][ts] = (f32x4){0.f, 0.f, 0.f, 0.f};
#pragma unroll
      for (int ks = 0; ks < 4; ++ks) {
        bf16x8 b0 = *reinterpret_cast<const bf16x8*>(&ZtT[lr][ks * 32 + lg * 8]);
        bf16x8 b1 = *reinterpret_cast<const bf16x8*>(&ZtT[16 + lr][ks * 32 + lg * 8]);
        bf16x8 b2 = *reinterpret_cast<const bf16x8*>(&ZtT[32 + lr][ks * 32 + lg * 8]);
        bf16x8 b3 = *reinterpret_cast<const bf16x8*>(&ZtT[48 + lr][ks * 32 + lg * 8]);
        acc[0][0] = __builtin_amdgcn_mfma_f32_16x16x32_bf16(ca[ks*2+0], b0, acc[0][0], 0, 0, 0);
        acc[0][1] = __builtin_amdgcn_mfma_f32_16x16x32_bf16(ca[ks*2+0], b1, acc[0][1], 0, 0, 0);
        acc[0][2] = __builtin_amdgcn_mfma_f32_16x16x32_bf16(ca[ks*2+0], b2, acc[0][2], 0, 0, 0);
        acc[0][3] = __builtin_amdgcn_mfma_f32_16x16x32_bf16(ca[ks*2+0], b3, acc[0][3], 0, 0, 0);
        acc[1][0] = __builtin_amdgcn_mfma_f32_16x16x32_bf16(ca[ks*2+1], b0, acc[1][0], 0, 0, 0);
        acc[1][1] = __builtin_amdgcn_mfma_f32_16x16x32_bf16(ca[ks*2+1], b1, acc[1][1], 0, 0, 0);
        acc[1][2] = __builtin_amdgcn_mfma_f32_16x16x32_bf16(ca[ks*2+1], b2, acc[1][2], 0, 0, 0);
        acc[1][3] = __builtin_amdgcn_mfma_f32_16x16x32_bf16(ca[ks*2+1], b3, acc[1][3], 0, 0, 0);
      }
#pragma unroll
      for (int ss = 0; ss < 2; ++ss)
#pragma unroll
        for (int ts = 0; ts < 4; ++ts)
#pragma unroll
          for (int r = 0; r < 4; ++r)
            acc[ss][ts][r] = fmaf(-2.f, acc[ss][ts][r],
                                  Cna[c * 128 + wv * 32 + ss * 16 + lg * 4 + r]);
#pragma unroll
      for (int ts = 0; ts < 4; ++ts) {
        int t = ts * 16 + lr;
        float thr = fdec(gminU[t]) + MARGIN;
#pragma unroll
        for (int ss = 0; ss < 2; ++ss)
#pragma unroll
          for (int r = 0; r < 4; ++r) {
            float v = acc[ss][ts][r];
            if (v <= thr) {
              int s = c * 128 + wv * 32 + ss * 16 + lg * 4 + r;
              int pos = atomicAdd(&fcnt[t], 1);
              if (pos < FCAP) fls[t][pos] = (unsigned short)s;
            }
          }
      }
    }
  }
  __syncthreads();   // scoring done; ZtT dead -> alias to Zl

  // ======== EPILOGUE: exact evaluation (bitwise round-6 numerics) ========
  auto Zl = reinterpret_cast<float(*)[64]>(smemU);              // 32 KB
  float* rm = &bestv[0][0];                                     // alias
  int*   ri = &bests[0][0];

  const int b = tok0 >> 12;
  const int tl = tid & 63, h = tid >> 6;
  if (tid == 0) ovn = 0;
  for (int rep = 0; rep < 8; ++rep) {   // stage z32 (= Acur) tile
    int idx = rep * 256 + tid;
    int d = idx >> 4, q = idx & 15;
    float4 v = *reinterpret_cast<const float4*>(Acur + (size_t)d * NTOK + tok0 + q * 4);
    Zl[d][q * 4 + 0] = v.x; Zl[d][q * 4 + 1] = v.y;
    Zl[d][q * 4 + 2] = v.z; Zl[d][q * 4 + 3] = v.w;
  }
  __syncthreads();
  {
    double s = 0.0;
#pragma unroll
    for (int dd = 0; dd < 32; ++dd) { double v = (double)Zl[h * 32 + dd][tl]; s += v * v; }
    znp[h][tl] = s;
  }
  __syncthreads();
  if (tid < 64) znl[tid] = (float)(((znp[0][tid] + znp[1][tid]) + znp[2][tid]) + znp[3][tid]);
  __syncthreads();
  const float zn = znl[tl];
  const int cnt = fcnt[tl];
  float bm = 3.4e38f; int bi = 0x7fffffff;
  if (cnt <= FCAP) {
    if (h == 0) ovf[tl] = 0;
    for (int i = h; i < cnt; i += 4) {
      int s = fls[tl][i];
      const float* cr = cbb + (size_t)s * CD;
      double e = 0.0;
      for (int d = 0; d < CD; ++d) e = fma((double)cr[d], (double)Zl[d][tl], e);
      float M = (float)e;
      float d2 = __fadd_rn(__fsub_rn(zn, __fmul_rn(2.f, M)), Cna[s]);
      if (d2 < bm || (d2 == bm && s < bi)) { bm = d2; bi = s; }
    }
  } else {
    if (h == 0) { int p = atomicAdd(&ovn, 1); ovl[p] = tl; ovf[tl] = 1; }
  }
  bestv[h][tl] = bm; bests[h][tl] = bi;
  __syncthreads();
  if (tid < 64 && !ovf[tid]) {
    float fv = bestv[0][tid]; int fs = bests[0][tid];
#pragma unroll
    for (int x = 1; x < 4; ++x) {
      float v = bestv[x][tid]; int s = bests[x][tid];
      if (v < fv || (v == fv && s < fs)) { fv = v; fs = s; }
    }
    codes[((size_t)b * NB + book) * T + ((tok0 + tid) & (T - 1))] = fs;
    scode[tid] = fs;
    lred[tid] = (double)fv;
  }
  __syncthreads();
  const int no = ovn;
  for (int e = 0; e < no; ++e) {
    const int tt = ovl[e];
    const float zn2 = znl[tt];
    double e0 = 0.0, e1 = 0.0, e2 = 0.0, e3 = 0.0;
    const float* c0 = cbb + (size_t)(tid      ) * CD;
    const float* c1 = cbb + (size_t)(tid + 256) * CD;
    const float* c2 = cbb + (size_t)(tid + 512) * CD;
    const float* c3 = cbb + (size_t)(tid + 768) * CD;
    for (int d = 0; d < CD; ++d) {
      double zv = (double)Zl[d][tt];
      e0 = fma((double)c0[d], zv, e0);
      e1 = fma((double)c1[d], zv, e1);
      e2 = fma((double)c2[d], zv, e2);
      e3 = fma((double)c3[d], zv, e3);
    }
    float bm2 = 3.4e38f; int bi2 = 0x7fffffff;
    {
      float d2;
      d2 = __fadd_rn(__fsub_rn(zn2, __fmul_rn(2.f, (float)e0)), Cna[tid]);
      if (d2 < bm2) { bm2 = d2; bi2 = tid; }
      d2 = __fadd_rn(__fsub_rn(zn2, __fmul_rn(2.f, (float)e1)), Cna[tid + 256]);
      if (d2 < bm2) { bm2 = d2; bi2 = tid + 256; }
      d2 = __fadd_rn(__fsub_rn(zn2, __fmul_rn(2.f, (float)e2)), Cna[tid + 512]);
      if (d2 < bm2) { bm2 = d2; bi2 = tid + 512; }
      d2 = __fadd_rn(__fsub_rn(zn2, __fmul_rn(2.f, (float)e3)), Cna[tid + 768]);
      if (d2 < bm2) { bm2 = d2; bi2 = tid + 768; }
    }
    rm[tid] = bm2; ri[tid] = bi2;
    __syncthreads();
    for (int off = 128; off; off >>= 1) {
      if (tid < off) {
        float om = rm[tid + off]; int oi = ri[tid + off];
        if (om < rm[tid] || (om == rm[tid] && oi < ri[tid])) { rm[tid] = om; ri[tid] = oi; }
      }
      __syncthreads();
    }
    if (tid == 0) {
      codes[((size_t)b * NB + book) * T + ((tok0 + tt) & (T - 1))] = ri[0];
      scode[tt] = ri[0];
      lred[tt] = (double)rm[0];
    }
    __syncthreads();
  }
  if (tid == 0) {
    double sum = 0.0;
    for (int i = 0; i < 64; ++i) sum += lred[i];
    lpartF[(size_t)book * 1024 + blockIdx.x] = sum;
  }

  // ======== ADVANCE (books 0..6): Acur -= PCF[code] ========
  if constexpr (!LAST) {
    __syncthreads();
    const int code = scode[tl];
    const float* pr = PCFb + (size_t)code * CD + h * 32;
#pragma unroll
    for (int d = 0; d < 32; ++d) {
      int dd = h * 32 + d;
      Acur[(size_t)dd * NTOK + tok0 + tl] = Zl[dd][tl] - pr[d];
    }
  }
}

// ---------------------------------------------------------------------------
// qs32[k][tok] = sum_books cb[book][code_book(tok)][k]   (fp32, z_q only)
__global__ __launch_bounds__(256) void qsgather_kernel(const float* __restrict__ cbs,
                                                       const int* __restrict__ codes,
                                                       float* __restrict__ qs32) {
  __shared__ int cds[64][8];
  const int tid = threadIdx.x;
  const int tok0 = blockIdx.x * 64;
  const int tl = tid & 63, h = tid >> 6;
  if (tid < 64) {
    int tok = tok0 + tid, b = tok >> 12, t = tok & (T - 1);
#pragma unroll
    for (int book = 0; book < NB; ++book)
      cds[tid][book] = codes[((size_t)b * NB + book) * T + t];
  }
  __syncthreads();
  const int tok = tok0 + tl;
  float acc[32] = {};
#pragma unroll
  for (int book = 0; book < NB; ++book) {
    const float* cr = cbs + ((size_t)book * S + cds[tl][book]) * CD + h * 32;
#pragma unroll
    for (int k = 0; k < 32; ++k) acc[k] += cr[k];
  }
#pragma unroll
  for (int k = 0; k < 32; ++k)
    qs32[(size_t)(h * 32 + k) * NTOK + tok] = acc[k];
}

// ---------------------------------------------------------------------------
// z_q (fp32, 2% tolerance)
__global__ __launch_bounds__(256) void final32_kernel(const float* __restrict__ qs32,
                                                      const float* __restrict__ WoutT,
                                                      const float* __restrict__ bout,
                                                      float* __restrict__ out) {
  __shared__ __align__(16) float Al[32][132];
  __shared__ __align__(16) float Bl[32][68];
  const int tid = threadIdx.x;
  const int t0 = blockIdx.x * 64;
  const int Dg = blockIdx.y;
  const int b  = blockIdx.z;
  const int mx = tid & 15, nx = tid >> 4;
  const size_t tokbase = (size_t)b * T + t0;
  float acc[8][4] = {};
  for (int kc = 0; kc < 4; ++kc) {
    __syncthreads();
#pragma unroll
    for (int rep = 0; rep < 4; ++rep) {
      int idx = rep * 256 + tid;
      int kk = idx >> 5, q = idx & 31;
      float4 v = *reinterpret_cast<const float4*>(
          WoutT + (size_t)(kc * 32 + kk) * 512 + Dg * 128 + q * 4);
      *reinterpret_cast<float4*>(&Al[kk][q * 4]) = v;
    }
#pragma unroll
    for (int rep = 0; rep < 2; ++rep) {
      int idx = rep * 256 + tid;
      int kk = idx >> 4, q = idx & 15;
      *reinterpret_cast<float4*>(&Bl[kk][q * 4]) =
          *reinterpret_cast<const float4*>(qs32 + (size_t)(kc * 32 + kk) * NTOK + tokbase + q * 4);
    }
    __syncthreads();
#pragma unroll
    for (int kk = 0; kk < 32; ++kk) {
      float4 a0 = *reinterpret_cast<const float4*>(&Al[kk][mx * 8]);
      float4 a1 = *reinterpret_cast<const float4*>(&Al[kk][mx * 8 + 4]);
      float4 bv = *reinterpret_cast<const float4*>(&Bl[kk][nx * 4]);
      float a[8] = {a0.x, a0.y, a0.z, a0.w, a1.x, a1.y, a1.z, a1.w};
      float bb[4] = {bv.x, bv.y, bv.z, bv.w};
#pragma unroll
      for (int u = 0; u < 8; ++u)
#pragma unroll
        for (int j = 0; j < 4; ++j) acc[u][j] = fmaf(a[u], bb[j], acc[u][j]);
    }
  }
#pragma unroll
  for (int u = 0; u < 8; ++u) {
    int D = Dg * 128 + mx * 8 + u;
    float bo = 8.0f * bout[D];
    float4 o = make_float4(acc[u][0] + bo, acc[u][1] + bo, acc[u][2] + bo, acc[u][3] + bo);
    reinterpret_cast<float4*>(out + ((size_t)b * DIN + D) * T + t0)[nx] = o;
  }
}

// ---------------------------------------------------------------------------
__global__ __launch_bounds__(256) void codes_out_kernel(const int* __restrict__ codes,
                                                        float* __restrict__ out) {
  int k = blockIdx.x * 256 + threadIdx.x;
  if (k < BATCH * NB * T)
    out[(size_t)BATCH * DIN * T + k] = (float)codes[k];
}

__global__ __launch_bounds__(256) void loss_out_kernel(const double* __restrict__ lpF,
                                                       float* __restrict__ out) {
  __shared__ double red[256];
  double s = 0.0;
  for (int i = threadIdx.x; i < NB * 1024; i += 256) s += lpF[i];
  red[threadIdx.x] = s;
  __syncthreads();
  for (int off = 128; off; off >>= 1) {
    if (threadIdx.x < off) red[threadIdx.x] += red[threadIdx.x + off];
    __syncthreads();
  }
  if (threadIdx.x == 0)
    out[(size_t)BATCH * DIN * T + (size_t)BATCH * NB * T] =
        (float)(red[0] * 1.25 / 8388608.0);
}

// ---------------------------------------------------------------------------
extern "C" void kernel_launch(void* const* d_in, const int* in_sizes, int n_in,
                              void* d_out, int out_size, void* d_ws, size_t ws_size,
                              hipStream_t stream) {
  (void)in_sizes; (void)n_in; (void)out_size; (void)ws_size;
  const float* z    = (const float*)d_in[0];
  const float* Win  = (const float*)d_in[1];
  const float* bin  = (const float*)d_in[2];
  const float* Wout = (const float*)d_in[3];
  const float* bout = (const float*)d_in[4];
  const float* cbs  = (const float*)d_in[5];
  float* out = (float*)d_out;
  float* Acur = out;   // fp32 running z_proj [d][tok] (33.6MB), aliases z_q region

  char* w = (char*)d_ws;
  double* P64t  = (double*)w;  w += (size_t)CD * CD * 8;
  double* cvec64= (double*)w;  w += CD * 8;
  double* lpartF= (double*)w;  w += (size_t)NB * 1024 * 8;
  float*  PCF32 = (float*)w;   w += (size_t)NB * S * CD * 4;      // 4.2 MB
  float*  qs32  = (float*)w;   w += (size_t)CD * NTOK * 4;        // 33.6 MB
  float*  cbn32 = (float*)w;   w += (size_t)NB * S * 4;
  float*  WinT  = (float*)w;   w += (size_t)DIN * CD * 4;         // 256 KB
  float*  WoutT = (float*)w;   w += (size_t)CD * DIN * 4;         // 256 KB
  unsigned short* cb16 = (unsigned short*)w; w += (size_t)NB * S * CD * 2; // 2.1 MB
  int*    codes = (int*)w;     w += (size_t)BATCH * NB * T * 4;

  cbn32_kernel<<<(NB * S + 255) / 256, 256, 0, stream>>>(cbs, cbn32);
  cb16_kernel<<<(NB * S * CD + 255) / 256, 256, 0, stream>>>(cbs, cb16);
  p64t_kernel<<<64, 256, 0, stream>>>(Win, Wout, P64t);
  cvec64_kernel<<<1, 128, 0, stream>>>(Win, bout, cvec64);
  pcf_kernel<<<dim3(S, NB), 128, 0, stream>>>(cbs, P64t, cvec64, PCF32);
  winT_kernel<<<256, 256, 0, stream>>>(Win, WinT);
  woutT_kernel<<<256, 256, 0, stream>>>(Wout, WoutT);
  a32_kernel<<<dim3(T / 64, BATCH), 256, 0, stream>>>(z, WinT, bin, Acur);

  for (int book = 0; book < NB; ++book) {
    const float* cb = cbs + (size_t)book * S * CD;
    const unsigned short* cbh = cb16 + (size_t)book * S * CD;
    if (book < NB - 1)
      fused_kernel<false><<<NTOK / 64, 256, 0, stream>>>(
          Acur, cbh, cb, cbn32 + book * S,
          PCF32 + (size_t)book * S * CD, codes, lpartF, book);
    else
      fused_kernel<true><<<NTOK / 64, 256, 0, stream>>>(
          Acur, cbh, cb, cbn32 + book * S,
          PCF32 + (size_t)book * S * CD, codes, lpartF, book);
  }
  qsgather_kernel<<<NTOK / 64, 256, 0, stream>>>(cbs, codes, qs32);
  final32_kernel<<<dim3(T / 64, DIN / 128, BATCH), 256, 0, stream>>>(qs32, WoutT, bout, out);
  codes_out_kernel<<<(BATCH * NB * T + 255) / 256, 256, 0, stream>>>(codes, out);
  loss_out_kernel<<<1, 256, 0, stream>>>(lpartF, out);
}